// Round 4
// baseline (407.912 us; speedup 1.0000x reference)
//
#include <hip/hip_runtime.h>
#include <hip/hip_bf16.h>

constexpr int kNodes = 100000;
constexpr int kEdges = 1600000;
constexpr int kCh    = 128;
constexpr int kCap   = 32;               // bucket row = 32 ints = one 128B line
constexpr int kOvfCap = 8192;            // overflow pairs; expected ~30 (Poisson(16) tail past 32)
constexpr int kPartSize = kNodes / 8;    // 12500 dst per XCD partition
constexpr int kBinBlocks = 128;          // 512 thr each -> 65536 binning threads
constexpr int kGemmBlocks = (kNodes + 127) / 128;  // 782
constexpr int kSegCap = 28672;           // per (part,xcd) segment; mean 25000, +25 sigma
constexpr int kFillBlocks = 512;         // 64 blocks per partition, 256 thr

typedef __attribute__((ext_vector_type(8))) short short8;
typedef __attribute__((ext_vector_type(4))) float floatx4;
typedef __attribute__((ext_vector_type(4))) int   intx4;

// =============== K1: edge binning (blocks [0,128)) + MFMA GEMM (rest) ===============
// Bin: read ei ONCE (no 8x rescan). Each wave ballots its 256-edge batch per partition,
// one atomicAdd per (wave,partition) reserves space in segment (p, xcd=blockIdx&7),
// writes packed (d<<32|s). GEMM: hs[n] = bf16(x[n] @ W), unscaled (dinv applied later).

__global__ __launch_bounds__(512) void k_bin_gemm(const float* __restrict__ x,
                                                  const float* __restrict__ W,
                                                  const int* __restrict__ srcArr,
                                                  const int* __restrict__ dstArr,
                                                  long* __restrict__ segs,
                                                  int* __restrict__ segCnt,
                                                  __hip_bfloat16* __restrict__ hs) {
  if (blockIdx.x < kBinBlocks) {
    int lane = threadIdx.x & 63;
    int xcd  = blockIdx.x & 7;
    const intx4* d4 = (const intx4*)dstArr;
    const intx4* s4 = (const intx4*)srcArr;
    constexpr int nQuads = kEdges / 4;              // 400000
    constexpr int stride = kBinBlocks * 512;        // 65536
    constexpr int rounds = (nQuads + stride - 1) / stride;  // 7
    unsigned long long lt = (1ull << lane) - 1;
    int i = blockIdx.x * 512 + threadIdx.x;
    for (int r = 0; r < rounds; r++, i += stride) {
      bool valid = i < nQuads;
      intx4 dv = {0, 0, 0, 0}, sv = {0, 0, 0, 0};
      if (valid) {
        dv = __builtin_nontemporal_load(d4 + i);
        sv = __builtin_nontemporal_load(s4 + i);
      }
      int part[4];
      #pragma unroll
      for (int k = 0; k < 4; k++) part[k] = valid ? (dv[k] / kPartSize) : 8;
      for (int p = 0; p < 8; p++) {
        unsigned long long m[4];
        #pragma unroll
        for (int k = 0; k < 4; k++) m[k] = __ballot(part[k] == p);
        int tot = __popcll(m[0]) + __popcll(m[1]) + __popcll(m[2]) + __popcll(m[3]);
        if (tot == 0) continue;                     // wave-uniform
        int base = 0;
        if (lane == 0) base = atomicAdd(&segCnt[(p * 8 + xcd) * 32], tot);
        base = __shfl(base, 0, 64);
        long* seg = segs + (long)(p * 8 + xcd) * kSegCap;
        int run = base;
        #pragma unroll
        for (int k = 0; k < 4; k++) {
          if (part[k] == p) {
            long e = ((long)dv[k] << 32) | (unsigned)sv[k];
            seg[run + __popcll(m[k] & lt)] = e;
          }
          run += __popcll(m[k]);
        }
      }
    }
    return;
  }

  // ---- GEMM: 8 waves, wave handles 16 rows; 8 N-tiles of 16; K=128 in 4 chunks ----
  __shared__ short8 Bf[2048];  // 32 KB, B-fragment order
  for (int e = threadIdx.x; e < 2048; e += 512) {
    int lane = e & 63, c = (e >> 6) & 3, tt = e >> 8;
    int quad = lane >> 4, mcol = lane & 15;
    short8 v;
    #pragma unroll
    for (int j = 0; j < 8; j++) {
      __hip_bfloat16 h = __float2bfloat16(W[(c * 32 + quad * 8 + j) * kCh + tt * 16 + mcol]);
      v[j] = *(short*)&h;
    }
    Bf[e] = v;
  }
  __syncthreads();

  int wave = threadIdx.x >> 6;
  int lane = threadIdx.x & 63;
  int quad = lane >> 4;
  int mcol = lane & 15;
  int gb = blockIdx.x - kBinBlocks;
  long rowBase = ((long)gb * 8 + wave) * 16;
  if (rowBase >= kNodes) return;

  long arow = rowBase + mcol;
  if (arow >= kNodes) arow = kNodes - 1;  // clamp (stores guarded)
  const float* xp = x + arow * kCh;
  short8 afrag[4];
  #pragma unroll
  for (int c = 0; c < 4; c++) {
    const floatx4* p = (const floatx4*)(xp + c * 32 + quad * 8);
    floatx4 v0 = __builtin_nontemporal_load(p);
    floatx4 v1 = __builtin_nontemporal_load(p + 1);
    #pragma unroll
    for (int j = 0; j < 4; j++) {
      __hip_bfloat16 h0 = __float2bfloat16(v0[j]);
      __hip_bfloat16 h1 = __float2bfloat16(v1[j]);
      afrag[c][j]     = *(short*)&h0;
      afrag[c][j + 4] = *(short*)&h1;
    }
  }

  #pragma unroll
  for (int t = 0; t < 8; t++) {
    floatx4 acc = {0.f, 0.f, 0.f, 0.f};
    #pragma unroll
    for (int c = 0; c < 4; c++) {
      short8 b = Bf[(t * 4 + c) * 64 + lane];  // stride-1 across lanes
      acc = __builtin_amdgcn_mfma_f32_16x16x32_bf16(afrag[c], b, acc, 0, 0, 0);
    }
    // C/D layout: col = lane&15, row = quad*4 + reg
    #pragma unroll
    for (int i = 0; i < 4; i++) {
      long r = rowBase + quad * 4 + i;
      if (r < kNodes) {
        __hip_bfloat16 h = __float2bfloat16(acc[i]);
        __builtin_nontemporal_store(*(short*)&h, (short*)hs + r * kCh + t * 16 + mcol);
      }
    }
  }
}

// =============== K2: scatter segments -> bucket (L2-local per XCD) + dinv tail ===============

__global__ __launch_bounds__(256) void k_fill(const long* __restrict__ segs,
                                              const int* __restrict__ segCnt,
                                              int* __restrict__ cnt,
                                              int* __restrict__ bucket,
                                              int* __restrict__ ovfCnt,
                                              int* __restrict__ ovfD,
                                              int* __restrict__ ovfS,
                                              int* __restrict__ partDone,
                                              float* __restrict__ dinv) {
  int p   = blockIdx.x & 7;       // partition == XCD (round-robin heuristic; correctness not dependent)
  int sub = blockIdx.x >> 3;      // 0..63
  for (int xs = 0; xs < 8; xs++) {
    int n = segCnt[(p * 8 + xs) * 32];
    if (n > kSegCap) n = kSegCap;
    const long* seg = segs + (long)(p * 8 + xs) * kSegCap;
    for (int i = sub * 256 + (int)threadIdx.x; i < n; i += 64 * 256) {
      long e = seg[i];
      int s = (int)(e & 0xffffffffL);
      int d = (int)(e >> 32);
      int pos = atomicAdd(&cnt[d], 1);
      if (pos < kCap) {
        bucket[(long)d * kCap + pos] = s;
      } else {
        int o = atomicAdd(ovfCnt, 1);
        if (o < kOvfCap) { ovfD[o] = d; ovfS[o] = s; }
      }
    }
  }

  // last block of this partition computes the dinv slice (atomic reads for coherence)
  __shared__ int lastFlag;
  __threadfence();
  __syncthreads();
  if (threadIdx.x == 0) lastFlag = (atomicAdd(&partDone[p * 32], 1) == 63);
  __syncthreads();
  if (lastFlag) {
    int lo = p * kPartSize;
    for (int i = threadIdx.x; i < kPartSize; i += 256) {
      int c = atomicAdd(&cnt[lo + i], 0);   // coherent read (same-kernel cross-block)
      dinv[lo + i] = rsqrtf((float)(c + 1));
    }
  }
}

// =============== K3: aggregation, one wave per dst node ===============
// out[d] = dinv[d] * ( dinv[d]*h[d] + sum_s dinv[s]*h[s] + overflow ) + bias
// dinv is a 400KB f32 table -> L2-resident, gathers are L2 hits; no per-edge rsqrt.

__global__ __launch_bounds__(256) void k_aggregate(const int* __restrict__ cnt,
                                                   const int* __restrict__ bucket,
                                                   const float* __restrict__ dinv,
                                                   const int* __restrict__ ovfCnt,
                                                   const int* __restrict__ ovfD,
                                                   const int* __restrict__ ovfS,
                                                   const __hip_bfloat16* __restrict__ hs,
                                                   const float* __restrict__ bias,
                                                   float* __restrict__ out) {
  int gid  = blockIdx.x * 256 + threadIdx.x;
  int node = gid >> 6;
  int lane = gid & 63;
  if (node >= kNodes) return;

  const __hip_bfloat162* hbase = (const __hip_bfloat162*)hs;

  int degRaw = cnt[node];
  float dd = dinv[node];

  float2 sf = __bfloat1622float2(hbase[(long)node * (kCh / 2) + lane]);
  float acc0 = dd * sf.x;
  float acc1 = dd * sf.y;

  int c = degRaw < kCap ? degRaw : kCap;
  const int* bkt = bucket + (long)node * kCap;

  int j = 0;
  for (; j + 7 < c; j += 8) {
    int s[8];
    #pragma unroll
    for (int u = 0; u < 8; u++) s[u] = bkt[j + u];
    float dv[8];
    #pragma unroll
    for (int u = 0; u < 8; u++) dv[u] = dinv[s[u]];
    __hip_bfloat162 v[8];
    #pragma unroll
    for (int u = 0; u < 8; u++) v[u] = hbase[(long)s[u] * (kCh / 2) + lane];
    #pragma unroll
    for (int u = 0; u < 8; u++) {
      float2 f = __bfloat1622float2(v[u]);
      acc0 = fmaf(dv[u], f.x, acc0);
      acc1 = fmaf(dv[u], f.y, acc1);
    }
  }
  for (; j < c; ++j) {
    int s = bkt[j];
    float dv = dinv[s];
    float2 f = __bfloat1622float2(hbase[(long)s * (kCh / 2) + lane]);
    acc0 = fmaf(dv, f.x, acc0);
    acc1 = fmaf(dv, f.y, acc1);
  }

  if (degRaw > kCap) {   // exact overflow handling (tiny list)
    int n = *ovfCnt;
    if (n > kOvfCap) n = kOvfCap;
    for (int i = 0; i < n; i++) {
      if (ovfD[i] == node) {
        int s = ovfS[i];
        float2 f = __bfloat1622float2(hbase[(long)s * (kCh / 2) + lane]);
        acc0 = fmaf(dinv[s], f.x, acc0);
        acc1 = fmaf(dinv[s], f.y, acc1);
      }
    }
  }

  float2 b = ((const float2*)bias)[lane];
  float2 o;
  o.x = dd * acc0 + b.x;
  o.y = dd * acc1 + b.y;
  ((float2*)(out + (long)node * kCh))[lane] = o;
}

// =============== launch ===============

extern "C" void kernel_launch(void* const* d_in, const int* in_sizes, int n_in,
                              void* d_out, int out_size, void* d_ws, size_t ws_size,
                              hipStream_t stream) {
  const float* x    = (const float*)d_in[0];
  const int*   ei   = (const int*)d_in[1];      // [2, E] row-major int32
  const float* W    = (const float*)d_in[2];
  const float* bias = (const float*)d_in[3];
  float* out = (float*)d_out;

  const int* srcArr = ei;
  const int* dstArr = ei + kEdges;

  // workspace layout (bytes)
  char* ws = (char*)d_ws;
  size_t off = 0;
  __hip_bfloat16* hs = (__hip_bfloat16*)(ws + off); off += (size_t)kNodes * kCh * 2;     // 25.6 MB
  int*   bucket  = (int*)  (ws + off); off += (size_t)kNodes * kCap * 4;                 // 12.8 MB
  long*  segs    = (long*) (ws + off); off += (size_t)64 * kSegCap * 8;                  // 14.7 MB
  float* dinv    = (float*)(ws + off); off += (size_t)kNodes * 4;                        // 0.4 MB
  // ---- zeroed region (one memset) ----
  char* zbase = ws + off;
  int*   cnt      = (int*)(ws + off); off += (size_t)kNodes * 4;                         // 0.4 MB
  int*   segCnt   = (int*)(ws + off); off += 64 * 32 * 4;                                // 8 KB padded
  int*   partDone = (int*)(ws + off); off += 8 * 32 * 4;                                 // 1 KB padded
  int*   ovfCnt   = (int*)(ws + off); off += 128;
  size_t zbytes = (size_t)((ws + off) - zbase);
  int*   ovfD     = (int*)(ws + off); off += (size_t)kOvfCap * 4;
  int*   ovfS     = (int*)(ws + off); off += (size_t)kOvfCap * 4;

  (void)hipMemsetAsync(zbase, 0, zbytes, stream);

  k_bin_gemm<<<kBinBlocks + kGemmBlocks, 512, 0, stream>>>(x, W, srcArr, dstArr,
                                                           segs, segCnt, hs);

  k_fill<<<kFillBlocks, 256, 0, stream>>>(segs, segCnt, cnt, bucket,
                                          ovfCnt, ovfD, ovfS, partDone, dinv);

  long aggThreads = (long)kNodes * 64;
  int gAgg = (int)((aggThreads + 255) / 256);
  k_aggregate<<<gAgg, 256, 0, stream>>>(cnt, bucket, dinv, ovfCnt, ovfD, ovfS,
                                        hs, bias, out);
}

// Round 5
// 265.378 us; speedup vs baseline: 1.5371x; 1.5371x over previous
//
#include <hip/hip_runtime.h>
#include <hip/hip_bf16.h>

constexpr int kNodes = 100000;
constexpr int kEdges = 1600000;
constexpr int kCh    = 128;
constexpr int kCap   = 32;               // bucket row = 32 ints = one 128B line
constexpr int kOvfCap = 8192;            // overflow pairs; expected ~handful (Poisson(16) tail past 32)
constexpr int kPartSize = kNodes / 8;    // 12500 dst per XCD partition
constexpr int kFillBlocks = 512;         // 64 blocks x 512 thr per partition
constexpr int kGemmBlocks = (kNodes + 127) / 128;  // 782

typedef __attribute__((ext_vector_type(8))) short short8;
typedef __attribute__((ext_vector_type(4))) float floatx4;
typedef __attribute__((ext_vector_type(4))) int   intx4;

// ---------------- fused fat kernel: bucket-CSR fill (blocks [0,512)) + MFMA GEMM (rest) --------
// Fill: XCD-partitioned by dst range (8x nt rescan of ei -- measured-best fill structure).
// GEMM: hs[n] = bf16(x[n] @ W), UNSCALED (dinv applied in aggregation), so no cnt dependency
// and the latency-bound fill waves overlap with the compute-bound MFMA waves.

__global__ __launch_bounds__(512) void k_fused(const float* __restrict__ x,
                                               const float* __restrict__ W,
                                               const int* __restrict__ srcArr,
                                               const int* __restrict__ dstArr,
                                               int* __restrict__ cnt,
                                               int* __restrict__ bucket,
                                               int* __restrict__ ovfCnt,
                                               int* __restrict__ ovfD,
                                               int* __restrict__ ovfS,
                                               __hip_bfloat16* __restrict__ hs) {
  if (blockIdx.x < kFillBlocks) {
    int part = blockIdx.x & 7;
    int bip  = blockIdx.x >> 3;          // 0..63 within partition
    int lo = part * kPartSize;
    const intx4* d4 = (const intx4*)dstArr;
    const intx4* s4 = (const intx4*)srcArr;
    for (int i = bip * 512 + (int)threadIdx.x; i < kEdges / 4; i += (kFillBlocks >> 3) * 512) {
      intx4 dv = __builtin_nontemporal_load(d4 + i);
      intx4 sv = __builtin_nontemporal_load(s4 + i);
      #pragma unroll
      for (int k = 0; k < 4; k++) {
        int d = dv[k];
        if ((unsigned)(d - lo) < (unsigned)kPartSize) {
          int pos = atomicAdd(&cnt[d], 1);
          if (pos < kCap) {
            bucket[(long)d * kCap + pos] = sv[k];
          } else {
            int o = atomicAdd(ovfCnt, 1);
            if (o < kOvfCap) { ovfD[o] = d; ovfS[o] = sv[k]; }
          }
        }
      }
    }
    return;
  }

  // ---- GEMM: 8 waves, wave handles 16 rows; 8 N-tiles of 16; K=128 in 4 chunks ----
  __shared__ short8 Bf[2048];  // 32 KB, B-fragment order
  for (int e = threadIdx.x; e < 2048; e += 512) {
    int lane = e & 63, c = (e >> 6) & 3, tt = e >> 8;
    int quad = lane >> 4, mcol = lane & 15;
    short8 v;
    #pragma unroll
    for (int j = 0; j < 8; j++) {
      __hip_bfloat16 h = __float2bfloat16(W[(c * 32 + quad * 8 + j) * kCh + tt * 16 + mcol]);
      v[j] = *(short*)&h;
    }
    Bf[e] = v;
  }
  __syncthreads();

  int wave = threadIdx.x >> 6;
  int lane = threadIdx.x & 63;
  int quad = lane >> 4;
  int mcol = lane & 15;
  int gb = blockIdx.x - kFillBlocks;
  long rowBase = ((long)gb * 8 + wave) * 16;
  if (rowBase >= kNodes) return;

  long arow = rowBase + mcol;
  if (arow >= kNodes) arow = kNodes - 1;  // clamp (stores guarded)
  const float* xp = x + arow * kCh;
  short8 afrag[4];
  #pragma unroll
  for (int c = 0; c < 4; c++) {
    const floatx4* p = (const floatx4*)(xp + c * 32 + quad * 8);
    floatx4 v0 = __builtin_nontemporal_load(p);
    floatx4 v1 = __builtin_nontemporal_load(p + 1);
    #pragma unroll
    for (int j = 0; j < 4; j++) {
      __hip_bfloat16 h0 = __float2bfloat16(v0[j]);
      __hip_bfloat16 h1 = __float2bfloat16(v1[j]);
      afrag[c][j]     = *(short*)&h0;
      afrag[c][j + 4] = *(short*)&h1;
    }
  }

  #pragma unroll
  for (int t = 0; t < 8; t++) {
    floatx4 acc = {0.f, 0.f, 0.f, 0.f};
    #pragma unroll
    for (int c = 0; c < 4; c++) {
      short8 b = Bf[(t * 4 + c) * 64 + lane];  // stride-1 across lanes
      acc = __builtin_amdgcn_mfma_f32_16x16x32_bf16(afrag[c], b, acc, 0, 0, 0);
    }
    // C/D layout: col = lane&15, row = quad*4 + reg
    #pragma unroll
    for (int i = 0; i < 4; i++) {
      long r = rowBase + quad * 4 + i;
      if (r < kNodes) {
        __hip_bfloat16 h = __float2bfloat16(acc[i]);
        __builtin_nontemporal_store(*(short*)&h, (short*)hs + r * kCh + t * 16 + mcol);
      }
    }
  }
}

// ---------------- tiny dinv table pass: dinv[i] = rsqrt(cnt[i]+1) ----------------

__global__ __launch_bounds__(256) void k_dinv(const int* __restrict__ cnt,
                                              float* __restrict__ dinv) {
  int i = blockIdx.x * 256 + threadIdx.x;
  if (i < kNodes) dinv[i] = rsqrtf((float)(cnt[i] + 1));
}

// ---------------- aggregation: one wave per dst node (dinv-table version) ----------------
// out[d] = dinv[d] * ( dinv[d]*h[d] + sum_s dinv[s]*h[s] + overflow ) + bias
// dinv is a 400KB f32 table -> L2-resident; no per-edge rsqrt / int-load chain.

__global__ __launch_bounds__(256) void k_aggregate(const int* __restrict__ cnt,
                                                   const int* __restrict__ bucket,
                                                   const float* __restrict__ dinv,
                                                   const int* __restrict__ ovfCnt,
                                                   const int* __restrict__ ovfD,
                                                   const int* __restrict__ ovfS,
                                                   const __hip_bfloat16* __restrict__ hs,
                                                   const float* __restrict__ bias,
                                                   float* __restrict__ out) {
  int gid  = blockIdx.x * 256 + threadIdx.x;
  int node = gid >> 6;
  int lane = gid & 63;
  if (node >= kNodes) return;

  const __hip_bfloat162* hbase = (const __hip_bfloat162*)hs;

  int degRaw = cnt[node];
  float dd = dinv[node];

  float2 sf = __bfloat1622float2(hbase[(long)node * (kCh / 2) + lane]);
  float acc0 = dd * sf.x;
  float acc1 = dd * sf.y;

  int c = degRaw < kCap ? degRaw : kCap;
  const int* bkt = bucket + (long)node * kCap;

  int j = 0;
  for (; j + 7 < c; j += 8) {
    int s[8];
    #pragma unroll
    for (int u = 0; u < 8; u++) s[u] = bkt[j + u];
    float dv[8];
    #pragma unroll
    for (int u = 0; u < 8; u++) dv[u] = dinv[s[u]];
    __hip_bfloat162 v[8];
    #pragma unroll
    for (int u = 0; u < 8; u++) v[u] = hbase[(long)s[u] * (kCh / 2) + lane];
    #pragma unroll
    for (int u = 0; u < 8; u++) {
      float2 f = __bfloat1622float2(v[u]);
      acc0 = fmaf(dv[u], f.x, acc0);
      acc1 = fmaf(dv[u], f.y, acc1);
    }
  }
  for (; j < c; ++j) {
    int s = bkt[j];
    float dv = dinv[s];
    float2 f = __bfloat1622float2(hbase[(long)s * (kCh / 2) + lane]);
    acc0 = fmaf(dv, f.x, acc0);
    acc1 = fmaf(dv, f.y, acc1);
  }

  if (degRaw > kCap) {   // exact overflow handling (tiny list)
    int n = *ovfCnt;
    if (n > kOvfCap) n = kOvfCap;
    for (int i = 0; i < n; i++) {
      if (ovfD[i] == node) {
        int s = ovfS[i];
        float2 f = __bfloat1622float2(hbase[(long)s * (kCh / 2) + lane]);
        acc0 = fmaf(dinv[s], f.x, acc0);
        acc1 = fmaf(dinv[s], f.y, acc1);
      }
    }
  }

  float2 b = ((const float2*)bias)[lane];
  float2 o;
  o.x = dd * acc0 + b.x;
  o.y = dd * acc1 + b.y;
  ((float2*)(out + (long)node * kCh))[lane] = o;
}

// ---------------- launch ----------------

extern "C" void kernel_launch(void* const* d_in, const int* in_sizes, int n_in,
                              void* d_out, int out_size, void* d_ws, size_t ws_size,
                              hipStream_t stream) {
  const float* x    = (const float*)d_in[0];
  const int*   ei   = (const int*)d_in[1];      // [2, E] row-major int32
  const float* W    = (const float*)d_in[2];
  const float* bias = (const float*)d_in[3];
  float* out = (float*)d_out;

  const int* srcArr = ei;
  const int* dstArr = ei + kEdges;

  // workspace layout (bytes)
  char* ws = (char*)d_ws;
  size_t off = 0;
  __hip_bfloat16* hs = (__hip_bfloat16*)(ws + off); off += (size_t)kNodes * kCh * 2;   // 25.6 MB
  int*   bucket  = (int*)  (ws + off); off += (size_t)kNodes * kCap * 4;               // 12.8 MB
  float* dinv    = (float*)(ws + off); off += (size_t)kNodes * 4;                      // 0.4 MB
  // ---- zeroed region (one memset) ----
  char* zbase = ws + off;
  int*   cnt     = (int*)(ws + off); off += (size_t)kNodes * 4;                        // 0.4 MB
  int*   ovfCnt  = (int*)(ws + off); off += 128;
  size_t zbytes = (size_t)((ws + off) - zbase);
  int*   ovfD    = (int*)(ws + off); off += (size_t)kOvfCap * 4;
  int*   ovfS    = (int*)(ws + off); off += (size_t)kOvfCap * 4;

  (void)hipMemsetAsync(zbase, 0, zbytes, stream);

  k_fused<<<kFillBlocks + kGemmBlocks, 512, 0, stream>>>(x, W, srcArr, dstArr, cnt, bucket,
                                                         ovfCnt, ovfD, ovfS, hs);

  k_dinv<<<(kNodes + 255) / 256, 256, 0, stream>>>(cnt, dinv);

  long aggThreads = (long)kNodes * 64;
  int gAgg = (int)((aggThreads + 255) / 256);
  k_aggregate<<<gAgg, 256, 0, stream>>>(cnt, bucket, dinv, ovfCnt, ovfD, ovfS,
                                        hs, bias, out);
}